// Round 3
// baseline (180.596 us; speedup 1.0000x reference)
//
#include <hip/hip_runtime.h>

// DemandMap: site_type_map (4096x4096 int32, row-major [x][y]) ->
// out [7][2048][2048] fp32 = bin_area(4.0) - per-type demand.
//
// Geometry collapse (verified R1, absmax=0.0): binW=binH=2, integer site
// coords, node sizes in [0,1) => each site overlaps exactly its home bin
// (x/2, y/2) with area ((x+nw)-x) * ((y+nh)-y) in fp32 (reference rounding).
// Maps 0..4 replicate type-1 demand, map 5 = type 2, map 6 = type 3.
//
// R3: same as R2 (8 y-bins/thread, nontemporal streaming) but using native
// clang ext_vector types for the nontemporal builtins (HIP_vector_type
// structs are rejected by __builtin_nontemporal_*).

constexpr int NBX  = 2048;
constexpr int NBY  = 2048;
constexpr int H    = 4096;             // site map height (y extent)
constexpr int MAPQ = NBX * NBY / 4;    // 16B-vector elements per output map

typedef int   vint4   __attribute__((ext_vector_type(4)));
typedef float vfloat4 __attribute__((ext_vector_type(4)));

__global__ __launch_bounds__(256) void demand_map_kernel(
    const int*   __restrict__ st,
    const float* __restrict__ nsx,
    const float* __restrict__ nsy,
    vfloat4*     __restrict__ out)
{
    const int tid = blockIdx.x * 256 + threadIdx.x;
    const int i   = tid >> 8;          // bin-x index (0..2047)
    const int jg  = tid & 255;         // group of 8 bins along y (0..255)

    const float nwx1 = nsx[1], nwx2 = nsx[2], nwx3 = nsx[3];
    const float nwy1 = nsy[1], nwy2 = nsy[2], nwy3 = nsy[3];

    const int   row0 = i * 2;
    const float xf0  = (float)row0;
    const float xf1  = (float)(row0 + 1);

    // per-row, per-type wx = (x + nw) - x  (reference fp32 rounding)
    const float wx0t1 = (xf0 + nwx1) - xf0, wx0t2 = (xf0 + nwx2) - xf0, wx0t3 = (xf0 + nwx3) - xf0;
    const float wx1t1 = (xf1 + nwx1) - xf1, wx1t2 = (xf1 + nwx2) - xf1, wx1t3 = (xf1 + nwx3) - xf1;

    // 16 sites from each of the two covered rows: 4 x 16B per row,
    // all 8 loads independent -> deep MLP. Nontemporal: read-once stream.
    const vint4* p0 = reinterpret_cast<const vint4*>(st + (size_t)row0 * H + 16 * jg);
    const vint4* p1 = reinterpret_cast<const vint4*>(st + ((size_t)row0 + 1) * H + 16 * jg);
    vint4 r0[4], r1[4];
    #pragma unroll
    for (int q = 0; q < 4; ++q) r0[q] = __builtin_nontemporal_load(p0 + q);
    #pragma unroll
    for (int q = 0; q < 4; ++q) r1[q] = __builtin_nontemporal_load(p1 + q);

    const int t0[16] = { r0[0].x, r0[0].y, r0[0].z, r0[0].w,
                         r0[1].x, r0[1].y, r0[1].z, r0[1].w,
                         r0[2].x, r0[2].y, r0[2].z, r0[2].w,
                         r0[3].x, r0[3].y, r0[3].z, r0[3].w };
    const int t1[16] = { r1[0].x, r1[0].y, r1[0].z, r1[0].w,
                         r1[1].x, r1[1].y, r1[1].z, r1[1].w,
                         r1[2].x, r1[2].y, r1[2].z, r1[2].w,
                         r1[3].x, r1[3].y, r1[3].z, r1[3].w };

    const int ybase = jg * 16;

    float v0[8], v5[8], v6[8];

    #pragma unroll
    for (int b = 0; b < 8; ++b) {
        float acc1 = 0.f, acc2 = 0.f, acc3 = 0.f;
        #pragma unroll
        for (int c = 0; c < 2; ++c) {
            const float yf = (float)(ybase + 2 * b + c);
            {   // row 0 site
                const int t = t0[2 * b + c];
                const float nh = (t == 1) ? nwy1 : ((t == 2) ? nwy2 : nwy3);
                const float wx = (t == 1) ? wx0t1 : ((t == 2) ? wx0t2 : wx0t3);
                const float a  = wx * ((yf + nh) - yf);
                acc1 += (t == 1) ? a : 0.f;
                acc2 += (t == 2) ? a : 0.f;
                acc3 += (t == 3) ? a : 0.f;
            }
            {   // row 1 site
                const int t = t1[2 * b + c];
                const float nh = (t == 1) ? nwy1 : ((t == 2) ? nwy2 : nwy3);
                const float wx = (t == 1) ? wx1t1 : ((t == 2) ? wx1t2 : wx1t3);
                const float a  = wx * ((yf + nh) - yf);
                acc1 += (t == 1) ? a : 0.f;
                acc2 += (t == 2) ? a : 0.f;
                acc3 += (t == 3) ? a : 0.f;
            }
        }
        v0[b] = 4.0f - acc1;
        v5[b] = 4.0f - acc2;
        v6[b] = 4.0f - acc3;
    }

    const vfloat4 V0a = { v0[0], v0[1], v0[2], v0[3] };
    const vfloat4 V0b = { v0[4], v0[5], v0[6], v0[7] };
    const vfloat4 V5a = { v5[0], v5[1], v5[2], v5[3] };
    const vfloat4 V5b = { v5[4], v5[5], v5[6], v5[7] };
    const vfloat4 V6a = { v6[0], v6[1], v6[2], v6[3] };
    const vfloat4 V6b = { v6[4], v6[5], v6[6], v6[7] };

    // out 16B-vector index: map*MAPQ + i*(NBY/4) + jg*2 (+1)
    const size_t obase = (size_t)i * (NBY / 4) + (size_t)jg * 2;
    #pragma unroll
    for (int m = 0; m < 5; ++m) {                 // maps 0..4 alias c0
        __builtin_nontemporal_store(V0a, out + (size_t)m * MAPQ + obase);
        __builtin_nontemporal_store(V0b, out + (size_t)m * MAPQ + obase + 1);
    }
    __builtin_nontemporal_store(V5a, out + (size_t)5 * MAPQ + obase);
    __builtin_nontemporal_store(V5b, out + (size_t)5 * MAPQ + obase + 1);
    __builtin_nontemporal_store(V6a, out + (size_t)6 * MAPQ + obase);
    __builtin_nontemporal_store(V6b, out + (size_t)6 * MAPQ + obase + 1);
}

extern "C" void kernel_launch(void* const* d_in, const int* in_sizes, int n_in,
                              void* d_out, int out_size, void* d_ws, size_t ws_size,
                              hipStream_t stream) {
    const int*   st  = (const int*)d_in[0];    // site_type_map, 4096*4096 int32
    const float* nsx = (const float*)d_in[1];  // node_size_x, 4 floats
    const float* nsy = (const float*)d_in[2];  // node_size_y, 4 floats
    vfloat4*     out = (vfloat4*)d_out;        // 7*2048*2048 fp32

    const int total_threads = NBX * (NBY / 8); // 2048 * 256 = 524,288
    const int block = 256;
    const int grid  = total_threads / block;   // 2048

    demand_map_kernel<<<grid, block, 0, stream>>>(st, nsx, nsy, out);
}